// Round 1
// baseline (3585.130 us; speedup 1.0000x reference)
//
#include <hip/hip_runtime.h>
#include <hip/hip_bf16.h>
#include <math.h>

// Problem constants (fixed by setup_inputs)
constexpr int Mr   = 16384;   // B*T
constexpr int Nn   = 4096;    // G*V
constexpr int Kk   = 1024;    // Din
constexpr int Gg   = 4;
constexpr int Vv   = 1024;
constexpr int Dd   = 128;

constexpr int BM = 64, BN = 64, BK = 16;

// ---------------------------------------------------------------------------
// Kernel 1: logits = inputs @ W + b, fp32 multiply / fp64 accumulate.
// Writes fp32 logits into the probs region of d_out.
// ---------------------------------------------------------------------------
__global__ __launch_bounds__(256) void gemm_logits(
    const float* __restrict__ A,   // [Mr][Kk]
    const float* __restrict__ W,   // [Kk][Nn]
    const float* __restrict__ bvec,// [Nn]
    float* __restrict__ C)         // [Mr][Nn]
{
    __shared__ float As[BK][BM];   // As[k][m] (transposed)
    __shared__ float Bs[BK][BN];   // Bs[k][n]

    const int tid = threadIdx.x;
    const int n0  = blockIdx.x * BN;
    const int m0  = blockIdx.y * BM;
    const int tx  = tid & 15;      // n-group
    const int ty  = tid >> 4;      // m-group

    // staging indices
    const int arow  = tid >> 2;          // 0..63  (m within tile)
    const int akq   = (tid & 3) << 2;    // 0,4,8,12 (k quad)
    const int bkrow = tid >> 4;          // 0..15 (k row)
    const int bnq   = (tid & 15) << 2;   // 0..60 (n quad)

    double acc[4][4];
#pragma unroll
    for (int i = 0; i < 4; i++)
#pragma unroll
        for (int j = 0; j < 4; j++) acc[i][j] = 0.0;

    for (int k0 = 0; k0 < Kk; k0 += BK) {
        float4 av = *(const float4*)(A + (size_t)(m0 + arow) * Kk + k0 + akq);
        float4 bv = *(const float4*)(W + (size_t)(k0 + bkrow) * Nn + n0 + bnq);
        __syncthreads();  // previous compute done before overwrite
        As[akq + 0][arow] = av.x;
        As[akq + 1][arow] = av.y;
        As[akq + 2][arow] = av.z;
        As[akq + 3][arow] = av.w;
        *(float4*)&Bs[bkrow][bnq] = bv;
        __syncthreads();

#pragma unroll
        for (int kk = 0; kk < BK; kk++) {
            float4 a4 = *(const float4*)&As[kk][ty << 2];
            float4 b4 = *(const float4*)&Bs[kk][tx << 2];
            double ad0 = (double)a4.x, ad1 = (double)a4.y,
                   ad2 = (double)a4.z, ad3 = (double)a4.w;
            double bd0 = (double)b4.x, bd1 = (double)b4.y,
                   bd2 = (double)b4.z, bd3 = (double)b4.w;
            acc[0][0] += ad0 * bd0; acc[0][1] += ad0 * bd1;
            acc[0][2] += ad0 * bd2; acc[0][3] += ad0 * bd3;
            acc[1][0] += ad1 * bd0; acc[1][1] += ad1 * bd1;
            acc[1][2] += ad1 * bd2; acc[1][3] += ad1 * bd3;
            acc[2][0] += ad2 * bd0; acc[2][1] += ad2 * bd1;
            acc[2][2] += ad2 * bd2; acc[2][3] += ad2 * bd3;
            acc[3][0] += ad3 * bd0; acc[3][1] += ad3 * bd1;
            acc[3][2] += ad3 * bd2; acc[3][3] += ad3 * bd3;
        }
    }

    float4 bb = *(const float4*)(bvec + n0 + (tx << 2));
#pragma unroll
    for (int i = 0; i < 4; i++) {
        const int m = m0 + (ty << 2) + i;
        float4 o;
        o.x = (float)(acc[i][0] + (double)bb.x);
        o.y = (float)(acc[i][1] + (double)bb.y);
        o.z = (float)(acc[i][2] + (double)bb.z);
        o.w = (float)(acc[i][3] + (double)bb.w);
        *(float4*)(C + (size_t)m * Nn + n0 + (tx << 2)) = o;
    }
}

// ---------------------------------------------------------------------------
// Kernel 2: per (b,t,g) row of V=1024:
//   l = (logit + gumbel)/TAU; argmax (first-index tie-break, exact fp64
//   recompute for near-ties); softmax probs (in-place over logits);
//   ids (float, -1 for padded); quantized = codebook[g, id] (0 for padded).
// ---------------------------------------------------------------------------
__global__ __launch_bounds__(256) void vq_epilogue(
    float* __restrict__ logits,        // [Mr*Gg][Vv], becomes probs in-place
    const float* __restrict__ gumbel,  // [Mr*Gg][Vv]
    const int* __restrict__ paddings,  // [Mr]
    const float* __restrict__ A,       // inputs [Mr][Kk]
    const float* __restrict__ Wm,      // [Kk][Nn]
    const float* __restrict__ bvec,    // [Nn]
    const float* __restrict__ codebook,// [Gg][Vv][Dd]
    float* __restrict__ ids_out,       // [Mr*Gg] as float
    float* __restrict__ quant_out)     // [Mr*Gg][Dd]
{
    const int idx = blockIdx.x;       // m*G + g
    const int m   = idx >> 2;
    const int g   = idx & 3;
    const int tid = threadIdx.x;
    float* row = logits + (size_t)idx * Vv;

    if (paddings[m] != 0) {
#pragma unroll
        for (int j = 0; j < 4; j++) row[tid + 256 * j] = 0.0f;
        if (tid == 0) ids_out[idx] = -1.0f;
        if (tid < Dd) quant_out[(size_t)idx * Dd + tid] = 0.0f;
        return;
    }

    const float* grow = gumbel + (size_t)idx * Vv;
    float lv[4];
    float bv1 = -1e30f, bv2 = -1e30f;
    int   bi1 = 0;
#pragma unroll
    for (int j = 0; j < 4; j++) {
        const int v = tid + 256 * j;
        const float l = (row[v] + grow[v]) * 0.5f;   // /TAU, TAU=2
        lv[j] = l;
        if (l > bv1) { bv2 = bv1; bv1 = l; bi1 = v; }   // increasing v: strict > keeps first idx
        else if (l > bv2) bv2 = l;
    }

    __shared__ float  s_v1[256];
    __shared__ float  s_v2[256];
    __shared__ int    s_i1[256];
    __shared__ double s_dv[256];

    s_v1[tid] = bv1; s_v2[tid] = bv2; s_i1[tid] = bi1;
    __syncthreads();
    for (int s = 128; s > 0; s >>= 1) {
        if (tid < s) {
            const float ov1 = s_v1[tid + s], ov2 = s_v2[tid + s];
            const int   oi1 = s_i1[tid + s];
            const float mv1 = s_v1[tid],     mv2 = s_v2[tid];
            const int   mi1 = s_i1[tid];
            if (ov1 > mv1 || (ov1 == mv1 && oi1 < mi1)) {
                s_v1[tid] = ov1; s_i1[tid] = oi1;
                s_v2[tid] = fmaxf(mv1, ov2);
            } else {
                s_v2[tid] = fmaxf(ov1, mv2);
            }
        }
        __syncthreads();
    }
    const float gmax = s_v1[0];
    const int   gidx = s_i1[0];
    const float gap  = gmax - s_v2[0];
    __syncthreads();

    int id = gidx;
    const float MARGIN = 1e-3f;
    if (gap < MARGIN) {
        // exact fp64 recompute of every candidate within MARGIN of the max
        double bdv = -1e300;
        int    bdi = 1 << 30;
#pragma unroll 1
        for (int j = 0; j < 4; j++) {
            const int v = tid + 256 * j;
            if (lv[j] >= gmax - MARGIN) {
                const float* arow = A + (size_t)m * Kk;
                const float* wcol = Wm + (g << 10) + v;
                double dot = 0.0;
                for (int k = 0; k < Kk; k++)
                    dot += (double)arow[k] * (double)wcol[(size_t)k * Nn];
                dot += (double)bvec[(g << 10) + v];
                const double val = (dot + (double)grow[v]) * 0.5;
                if (val > bdv || (val == bdv && v < bdi)) { bdv = val; bdi = v; }
            }
        }
        s_dv[tid] = bdv; s_i1[tid] = bdi;
        __syncthreads();
        for (int s = 128; s > 0; s >>= 1) {
            if (tid < s) {
                const double o  = s_dv[tid + s];
                const int    oi = s_i1[tid + s];
                if (o > s_dv[tid] || (o == s_dv[tid] && oi < s_i1[tid])) {
                    s_dv[tid] = o; s_i1[tid] = oi;
                }
            }
            __syncthreads();
        }
        id = s_i1[0];
        __syncthreads();
    }

    // softmax (in-place over logits row)
    float ev[4];
    float se = 0.f;
#pragma unroll
    for (int j = 0; j < 4; j++) { ev[j] = expf(lv[j] - gmax); se += ev[j]; }
    s_v1[tid] = se;
    __syncthreads();
    for (int s = 128; s > 0; s >>= 1) {
        if (tid < s) s_v1[tid] += s_v1[tid + s];
        __syncthreads();
    }
    const float inv = 1.0f / s_v1[0];
#pragma unroll
    for (int j = 0; j < 4; j++) row[tid + 256 * j] = ev[j] * inv;

    if (tid == 0) ids_out[idx] = (float)id;
    if (tid < Dd)
        quant_out[(size_t)idx * Dd + tid] =
            codebook[(size_t)(((g << 10) + id) << 7) + tid];
}

// ---------------------------------------------------------------------------
extern "C" void kernel_launch(void* const* d_in, const int* in_sizes, int n_in,
                              void* d_out, int out_size, void* d_ws, size_t ws_size,
                              hipStream_t stream) {
    const float* inputs   = (const float*)d_in[0];
    const int*   paddings = (const int*)d_in[1];
    const float* gumbel   = (const float*)d_in[2];
    const float* W        = (const float*)d_in[3];
    const float* bvec     = (const float*)d_in[4];
    const float* codebook = (const float*)d_in[5];

    float* out       = (float*)d_out;
    float* ids_out   = out;                                  // 65536
    float* quant_out = out + (size_t)Mr * Gg;                // 8388608
    float* probs_out = out + (size_t)Mr * Gg + (size_t)Mr * Gg * Dd; // 67108864

    // Kernel 1: logits into probs region
    dim3 g1(Nn / BN, Mr / BM);
    gemm_logits<<<g1, 256, 0, stream>>>(inputs, W, bvec, probs_out);

    // Kernel 2: fused gumbel/argmax/softmax/quantize (probs in-place)
    vq_epilogue<<<Mr * Gg, 256, 0, stream>>>(probs_out, gumbel, paddings,
                                             inputs, W, bvec, codebook,
                                             ids_out, quant_out);
}

// Round 2
// 928.424 us; speedup vs baseline: 3.8615x; 3.8615x over previous
//
#include <hip/hip_runtime.h>
#include <hip/hip_bf16.h>
#include <math.h>

// Problem constants (fixed by setup_inputs)
constexpr int Mr = 16384;   // B*T
constexpr int Nn = 4096;    // G*V
constexpr int Kk = 1024;    // Din
constexpr int Gg = 4;
constexpr int Vv = 1024;
constexpr int Dd = 128;

typedef __attribute__((ext_vector_type(8))) short bf16x8;
typedef __attribute__((ext_vector_type(4))) float f32x4;

__device__ inline ushort f32_to_bf16(float x) {
    unsigned u = __float_as_uint(x);
    u += 0x7FFFu + ((u >> 16) & 1u);
    return (ushort)(u >> 16);
}

constexpr int LDK = 40;  // padded k-stride in ushorts (80 B: 16B-aligned rows, conflict-free b128 frag reads)

// ---------------------------------------------------------------------------
// Kernel 1: logits = bf16(inputs) @ bf16(W) + b via MFMA, fp32 accumulate.
// 128x128 tile, BK=32, 4 waves (2x2), 4x4 mfma_f32_16x16x32_bf16 per wave.
// ---------------------------------------------------------------------------
__global__ __launch_bounds__(256, 2) void gemm_logits_bf16(
    const float* __restrict__ A,    // [Mr][Kk]
    const float* __restrict__ W,    // [Kk][Nn]
    const float* __restrict__ bvec, // [Nn]
    float* __restrict__ C)          // [Mr][Nn]
{
    __shared__ ushort Ah[128 * LDK];  // [m][k] bf16
    __shared__ ushort Bh[128 * LDK];  // [n][k] bf16 (transposed W tile)

    const int tid  = threadIdx.x;
    const int lane = tid & 63;
    const int w    = tid >> 6;
    const int wm   = w >> 1;          // wave m (0..1)
    const int wn   = w & 1;           // wave n (0..1)
    const int quad = lane >> 4;
    const int l16  = lane & 15;

    const int m0 = blockIdx.y * 128;
    const int n0 = blockIdx.x * 128;

    // A staging: thread -> 4 float4; row = (t>>3)+32j, col4 = t&7
    const int a_row = tid >> 3;       // 0..31
    const int a_c4  = tid & 7;        // 0..7
    // B staging: per-column loads; n = t&127, kq = (t>>7) + 2j (kq 0..7)
    const int b_n   = tid & 127;
    const int b_kq0 = tid >> 7;

    f32x4 acc[4][4];
#pragma unroll
    for (int i = 0; i < 4; i++)
#pragma unroll
        for (int j = 0; j < 4; j++) acc[i][j] = (f32x4)(0.0f);

    float4 areg[4];
    float  breg[4][4];

    // prologue: load k0 = 0
#pragma unroll
    for (int j = 0; j < 4; j++)
        areg[j] = *(const float4*)(A + (size_t)(m0 + a_row + 32 * j) * Kk + a_c4 * 4);
#pragma unroll
    for (int j = 0; j < 4; j++) {
        const int kq = b_kq0 + 2 * j;
#pragma unroll
        for (int r = 0; r < 4; r++)
            breg[j][r] = W[(size_t)(kq * 4 + r) * Nn + n0 + b_n];
    }

    for (int k0 = 0; k0 < Kk; k0 += 32) {
        __syncthreads();  // previous iter's frag reads done
        // convert + write LDS
#pragma unroll
        for (int j = 0; j < 4; j++) {
            ushort4 h;
            h.x = f32_to_bf16(areg[j].x);
            h.y = f32_to_bf16(areg[j].y);
            h.z = f32_to_bf16(areg[j].z);
            h.w = f32_to_bf16(areg[j].w);
            *(ushort4*)&Ah[(a_row + 32 * j) * LDK + a_c4 * 4] = h;
        }
#pragma unroll
        for (int j = 0; j < 4; j++) {
            const int kq = b_kq0 + 2 * j;
            ushort4 h;
            h.x = f32_to_bf16(breg[j][0]);
            h.y = f32_to_bf16(breg[j][1]);
            h.z = f32_to_bf16(breg[j][2]);
            h.w = f32_to_bf16(breg[j][3]);
            *(ushort4*)&Bh[b_n * LDK + kq * 4] = h;
        }
        __syncthreads();

        // prefetch next k-slice into regs (overlaps MFMA below)
        if (k0 + 32 < Kk) {
            const int kn = k0 + 32;
#pragma unroll
            for (int j = 0; j < 4; j++)
                areg[j] = *(const float4*)(A + (size_t)(m0 + a_row + 32 * j) * Kk + kn + a_c4 * 4);
#pragma unroll
            for (int j = 0; j < 4; j++) {
                const int kq = b_kq0 + 2 * j;
#pragma unroll
                for (int r = 0; r < 4; r++)
                    breg[j][r] = W[(size_t)(kn + kq * 4 + r) * Nn + n0 + b_n];
            }
        }

        // fragment loads (conflict-free b128)
        bf16x8 af[4], bf[4];
#pragma unroll
        for (int mi = 0; mi < 4; mi++)
            af[mi] = *(const bf16x8*)&Ah[(wm * 64 + mi * 16 + l16) * LDK + quad * 8];
#pragma unroll
        for (int ni = 0; ni < 4; ni++)
            bf[ni] = *(const bf16x8*)&Bh[(wn * 64 + ni * 16 + l16) * LDK + quad * 8];

#pragma unroll
        for (int mi = 0; mi < 4; mi++)
#pragma unroll
            for (int ni = 0; ni < 4; ni++)
                acc[mi][ni] = __builtin_amdgcn_mfma_f32_16x16x32_bf16(
                    af[mi], bf[ni], acc[mi][ni], 0, 0, 0);
    }

    // epilogue: bias + store (D: row = quad*4 + r, col = l16)
    float bb[4];
#pragma unroll
    for (int ni = 0; ni < 4; ni++)
        bb[ni] = bvec[n0 + wn * 64 + ni * 16 + l16];
#pragma unroll
    for (int mi = 0; mi < 4; mi++) {
        const int mbase = m0 + wm * 64 + mi * 16 + quad * 4;
#pragma unroll
        for (int ni = 0; ni < 4; ni++) {
            const int n = n0 + wn * 64 + ni * 16 + l16;
            float* cp = C + (size_t)mbase * Nn + n;
#pragma unroll
            for (int r = 0; r < 4; r++)
                cp[(size_t)r * Nn] = acc[mi][ni][r] + bb[ni];
        }
    }
}

// ---------------------------------------------------------------------------
// Kernel 2: per (b,t,g) row of V=1024:
//   l = (logit + gumbel)/TAU; argmax (first-index tie-break; exact fp64
//   recompute for near-ties within MARGIN); softmax in-place; ids; quantized.
// ---------------------------------------------------------------------------
__global__ __launch_bounds__(256) void vq_epilogue(
    float* __restrict__ logits,        // [Mr*Gg][Vv] -> probs in-place
    const float* __restrict__ gumbel,  // [Mr*Gg][Vv]
    const int* __restrict__ paddings,  // [Mr]
    const float* __restrict__ A,       // inputs [Mr][Kk]
    const float* __restrict__ Wm,      // [Kk][Nn]
    const float* __restrict__ bvec,    // [Nn]
    const float* __restrict__ codebook,// [Gg][Vv][Dd]
    float* __restrict__ ids_out,       // [Mr*Gg] as float
    float* __restrict__ quant_out)     // [Mr*Gg][Dd]
{
    const int idx = blockIdx.x;       // m*G + g
    const int m   = idx >> 2;
    const int g   = idx & 3;
    const int tid = threadIdx.x;
    float* row = logits + (size_t)idx * Vv;

    if (paddings[m] != 0) {
        *(float4*)(row + tid * 4) = float4{0.f, 0.f, 0.f, 0.f};
        if (tid == 0) ids_out[idx] = -1.0f;
        if (tid < 32) *(float4*)(quant_out + (size_t)idx * Dd + tid * 4) = float4{0.f, 0.f, 0.f, 0.f};
        return;
    }

    const float* grow = gumbel + (size_t)idx * Vv;
    const float4 lr = *(const float4*)(row + tid * 4);
    const float4 gr = *(const float4*)(grow + tid * 4);
    float lv[4] = {(lr.x + gr.x) * 0.5f, (lr.y + gr.y) * 0.5f,
                   (lr.z + gr.z) * 0.5f, (lr.w + gr.w) * 0.5f};

    float bv1 = -1e30f, bv2 = -1e30f;
    int   bi1 = 0;
#pragma unroll
    for (int j = 0; j < 4; j++) {
        const int v = tid * 4 + j;
        if (lv[j] > bv1) { bv2 = bv1; bv1 = lv[j]; bi1 = v; }
        else if (lv[j] > bv2) bv2 = lv[j];
    }

    __shared__ float  s_v1[256];
    __shared__ float  s_v2[256];
    __shared__ int    s_i1[256];
    __shared__ double s_dv[256];

    s_v1[tid] = bv1; s_v2[tid] = bv2; s_i1[tid] = bi1;
    __syncthreads();
    for (int s = 128; s > 0; s >>= 1) {
        if (tid < s) {
            const float ov1 = s_v1[tid + s], ov2 = s_v2[tid + s];
            const int   oi1 = s_i1[tid + s];
            const float mv1 = s_v1[tid];
            const int   mi1 = s_i1[tid];
            if (ov1 > mv1 || (ov1 == mv1 && oi1 < mi1)) {
                s_v1[tid] = ov1; s_i1[tid] = oi1;
                s_v2[tid] = fmaxf(mv1, ov2);
            } else {
                s_v2[tid] = fmaxf(ov1, s_v2[tid]);
            }
        }
        __syncthreads();
    }
    const float gmax = s_v1[0];
    const int   gidx = s_i1[0];
    const float gap  = gmax - s_v2[0];
    __syncthreads();

    int id = gidx;
    const float MARGIN = 0.02f;   // >= 2x worst bf16-GEMM logit error (~7e-3 full-scale)
    if (gap < MARGIN) {
        // exact fp64 recompute of every candidate within MARGIN of the max
        double bdv = -1e300;
        int    bdi = 1 << 30;
#pragma unroll 1
        for (int j = 0; j < 4; j++) {
            const int v = tid * 4 + j;
            if (lv[j] >= gmax - MARGIN) {
                const float* arow = A + (size_t)m * Kk;
                const float* wcol = Wm + (g << 10) + v;
                double dot = 0.0;
                for (int k = 0; k < Kk; k++)
                    dot += (double)arow[k] * (double)wcol[(size_t)k * Nn];
                dot += (double)bvec[(g << 10) + v];
                const double val = (dot + (double)grow[v]) * 0.5;
                if (val > bdv || (val == bdv && v < bdi)) { bdv = val; bdi = v; }
            }
        }
        s_dv[tid] = bdv; s_i1[tid] = bdi;
        __syncthreads();
        for (int s = 128; s > 0; s >>= 1) {
            if (tid < s) {
                const double o  = s_dv[tid + s];
                const int    oi = s_i1[tid + s];
                if (o > s_dv[tid] || (o == s_dv[tid] && oi < s_i1[tid])) {
                    s_dv[tid] = o; s_i1[tid] = oi;
                }
            }
            __syncthreads();
        }
        id = s_i1[0];
        __syncthreads();
    }

    // softmax (in-place over logits row)
    float ev[4];
    float se = 0.f;
#pragma unroll
    for (int j = 0; j < 4; j++) { ev[j] = __expf(lv[j] - gmax); se += ev[j]; }
    s_v1[tid] = se;
    __syncthreads();
    for (int s = 128; s > 0; s >>= 1) {
        if (tid < s) s_v1[tid] += s_v1[tid + s];
        __syncthreads();
    }
    const float inv = 1.0f / s_v1[0];
    *(float4*)(row + tid * 4) = float4{ev[0] * inv, ev[1] * inv, ev[2] * inv, ev[3] * inv};

    if (tid == 0) ids_out[idx] = (float)id;
    if (tid < 32)
        *(float4*)(quant_out + (size_t)idx * Dd + tid * 4) =
            *(const float4*)(codebook + (size_t)(((g << 10) + id) << 7) + tid * 4);
}

// ---------------------------------------------------------------------------
extern "C" void kernel_launch(void* const* d_in, const int* in_sizes, int n_in,
                              void* d_out, int out_size, void* d_ws, size_t ws_size,
                              hipStream_t stream) {
    const float* inputs   = (const float*)d_in[0];
    const int*   paddings = (const int*)d_in[1];
    const float* gumbel   = (const float*)d_in[2];
    const float* W        = (const float*)d_in[3];
    const float* bvec     = (const float*)d_in[4];
    const float* codebook = (const float*)d_in[5];

    float* out       = (float*)d_out;
    float* ids_out   = out;                                           // 65536
    float* quant_out = out + (size_t)Mr * Gg;                         // 8388608
    float* probs_out = out + (size_t)Mr * Gg + (size_t)Mr * Gg * Dd;  // 67108864

    // Kernel 1: logits into probs region (bf16 MFMA)
    dim3 g1(Nn / 128, Mr / 128);
    gemm_logits_bf16<<<g1, 256, 0, stream>>>(inputs, W, bvec, probs_out);

    // Kernel 2: fused gumbel/argmax/softmax/quantize (probs in-place)
    vq_epilogue<<<Mr * Gg, 256, 0, stream>>>(probs_out, gumbel, paddings,
                                             inputs, W, bvec, codebook,
                                             ids_out, quant_out);
}